// Round 1
// baseline (141.323 us; speedup 1.0000x reference)
//
#include <hip/hip_runtime.h>

#define SLEN  2048
#define DHEAD 64
#define QB    64     // q rows per block
#define KT    64     // kv rows per tile
#define NWAVES 4
#define LROW  72     // padded LDS row (bf16 elems): +8 pad -> 2-way bank alias (free)

typedef short bf16x8 __attribute__((ext_vector_type(8)));
typedef float f32x4  __attribute__((ext_vector_type(4)));

static __device__ __forceinline__ unsigned short f2bf(float f) {
    union { float f; unsigned int u; } x; x.f = f;
    unsigned int r = (x.u + 0x7FFFu + ((x.u >> 16) & 1u)) >> 16;  // RNE
    return (unsigned short)r;
}

__global__ __launch_bounds__(256)
void sdpa_fwd(const float* __restrict__ Q, const float* __restrict__ K,
              const float* __restrict__ V, const float* __restrict__ M,
              float* __restrict__ O)
{
    __shared__ unsigned short Klds[KT][LROW];        // K tile, row-major [kv][d]
    __shared__ unsigned short Vt[DHEAD][LROW];       // V tile, transposed [d][kv]
    __shared__ unsigned short Plds[NWAVES][16][LROW];// per-wave P relayout buffer

    const int tid  = threadIdx.x;
    const int wave = tid >> 6;
    const int lane = tid & 63;
    const int lg   = lane >> 4;   // lane group 0..3
    const int ln   = lane & 15;

    const int qtile = blockIdx.x;
    const int bh    = blockIdx.y;
    const int qbase = qtile * QB + wave * 16;     // this wave's first q row
    const size_t hoff = (size_t)bh * SLEN * DHEAD;

    // ---- Q fragments (A layout: row = ln, k = 32*ks + 8*lg + j), pre-scaled ----
    bf16x8 qf[2];
    {
        const float* qp = Q + hoff + (size_t)(qbase + ln) * DHEAD;
        #pragma unroll
        for (int ks = 0; ks < 2; ++ks) {
            float4 a = *(const float4*)(qp + ks*32 + lg*8);
            float4 b = *(const float4*)(qp + ks*32 + lg*8 + 4);
            qf[ks][0] = (short)f2bf(a.x * 0.125f);
            qf[ks][1] = (short)f2bf(a.y * 0.125f);
            qf[ks][2] = (short)f2bf(a.z * 0.125f);
            qf[ks][3] = (short)f2bf(a.w * 0.125f);
            qf[ks][4] = (short)f2bf(b.x * 0.125f);
            qf[ks][5] = (short)f2bf(b.y * 0.125f);
            qf[ks][6] = (short)f2bf(b.z * 0.125f);
            qf[ks][7] = (short)f2bf(b.w * 0.125f);
        }
    }

    // ---- online-softmax state (C/D layout: this lane covers rows 4*lg+i) ----
    f32x4 oacc[4];                 // [d-chunk][reg]; out tile 16q x 64d
    #pragma unroll
    for (int dn = 0; dn < 4; ++dn) oacc[dn] = (f32x4){0.f, 0.f, 0.f, 0.f};
    float m_i[4] = {-INFINITY, -INFINITY, -INFINITY, -INFINITY};
    float l_i[4] = {0.f, 0.f, 0.f, 0.f};

    for (int kt = 0; kt < SLEN / KT; ++kt) {
        const int kbase = kt * KT;

        __syncthreads();  // protect LDS from previous iteration's readers

        // ---- stage K (row-major) and V (transposed) tiles, fp32 -> bf16 ----
        {
            const float* kp = K + hoff + (size_t)kbase * DHEAD;
            const float* vp = V + hoff + (size_t)kbase * DHEAD;
            #pragma unroll
            for (int it = 0; it < 4; ++it) {
                int flat = it * 1024 + tid * 4;
                int r = flat >> 6;       // kv row in tile
                int c = flat & 63;       // d column
                float4 kv4 = *(const float4*)(kp + flat);
                float4 vv4 = *(const float4*)(vp + flat);
                ushort4 kb;
                kb.x = f2bf(kv4.x); kb.y = f2bf(kv4.y);
                kb.z = f2bf(kv4.z); kb.w = f2bf(kv4.w);
                *(ushort4*)&Klds[r][c] = kb;
                Vt[c + 0][r] = f2bf(vv4.x);
                Vt[c + 1][r] = f2bf(vv4.y);
                Vt[c + 2][r] = f2bf(vv4.z);
                Vt[c + 3][r] = f2bf(vv4.w);
            }
        }
        __syncthreads();

        // ---- QK^T: S[16 q][64 kv] as 4 n-tiles ----
        f32x4 sc[4];
        #pragma unroll
        for (int nt = 0; nt < 4; ++nt) {
            f32x4 acc = (f32x4){0.f, 0.f, 0.f, 0.f};
            #pragma unroll
            for (int ks = 0; ks < 2; ++ks) {
                bf16x8 kf = *(const bf16x8*)&Klds[nt*16 + ln][ks*32 + lg*8];
                acc = __builtin_amdgcn_mfma_f32_16x16x32_bf16(qf[ks], kf, acc, 0, 0, 0);
            }
            sc[nt] = acc;
        }

        // ---- additive mask (broadcast over B,H): mask[qrow][kcol] ----
        #pragma unroll
        for (int i = 0; i < 4; ++i) {
            const float* mrow = M + (size_t)(qbase + 4*lg + i) * SLEN + kbase;
            #pragma unroll
            for (int nt = 0; nt < 4; ++nt)
                sc[nt][i] += mrow[nt*16 + ln];
        }

        // ---- online softmax: row max / rescale / exp / row sum ----
        float mnew[4], alpha[4];
        #pragma unroll
        for (int i = 0; i < 4; ++i) {
            float tm = fmaxf(fmaxf(sc[0][i], sc[1][i]), fmaxf(sc[2][i], sc[3][i]));
            tm = fmaxf(tm, __shfl_xor(tm, 1));
            tm = fmaxf(tm, __shfl_xor(tm, 2));
            tm = fmaxf(tm, __shfl_xor(tm, 4));
            tm = fmaxf(tm, __shfl_xor(tm, 8));
            mnew[i]  = fmaxf(m_i[i], tm);
            alpha[i] = __expf(m_i[i] - mnew[i]);
            m_i[i]   = mnew[i];
        }

        #pragma unroll
        for (int nt = 0; nt < 4; ++nt) {
            #pragma unroll
            for (int i = 0; i < 4; ++i) {
                float p = __expf(sc[nt][i] - mnew[i]);
                sc[nt][i] = p;
                Plds[wave][4*lg + i][nt*16 + ln] = f2bf(p);
            }
        }

        #pragma unroll
        for (int i = 0; i < 4; ++i) {
            float ts = (sc[0][i] + sc[1][i]) + (sc[2][i] + sc[3][i]);
            ts += __shfl_xor(ts, 1);
            ts += __shfl_xor(ts, 2);
            ts += __shfl_xor(ts, 4);
            ts += __shfl_xor(ts, 8);
            l_i[i] = l_i[i] * alpha[i] + ts;
            #pragma unroll
            for (int dn = 0; dn < 4; ++dn) oacc[dn][i] *= alpha[i];
        }

        // ---- PV: O[16 q][64 d] += P[16][64] * V[64][64] ----
        #pragma unroll
        for (int ks = 0; ks < 2; ++ks) {
            bf16x8 pa = *(const bf16x8*)&Plds[wave][ln][ks*32 + lg*8];
            #pragma unroll
            for (int dn = 0; dn < 4; ++dn) {
                bf16x8 vb = *(const bf16x8*)&Vt[dn*16 + ln][ks*32 + lg*8];
                oacc[dn] = __builtin_amdgcn_mfma_f32_16x16x32_bf16(pa, vb, oacc[dn], 0, 0, 0);
            }
        }
    }

    // ---- epilogue: normalize by l, store fp32 ----
    #pragma unroll
    for (int i = 0; i < 4; ++i) {
        float inv = 1.0f / l_i[i];
        float* op = O + hoff + (size_t)(qbase + 4*lg + i) * DHEAD;
        #pragma unroll
        for (int dn = 0; dn < 4; ++dn)
            op[dn*16 + ln] = oacc[dn][i] * inv;
    }
}

extern "C" void kernel_launch(void* const* d_in, const int* in_sizes, int n_in,
                              void* d_out, int out_size, void* d_ws, size_t ws_size,
                              hipStream_t stream) {
    const float* q = (const float*)d_in[0];
    const float* k = (const float*)d_in[1];
    const float* v = (const float*)d_in[2];
    const float* m = (const float*)d_in[3];
    float* o = (float*)d_out;

    const int bh = in_sizes[0] / (SLEN * DHEAD);   // B*H = 24
    dim3 grid(SLEN / QB, bh);
    sdpa_fwd<<<grid, 256, 0, stream>>>(q, k, v, m, o);
}

// Round 2
// 106.652 us; speedup vs baseline: 1.3251x; 1.3251x over previous
//
#include <hip/hip_runtime.h>
#include <stdint.h>

#define SLEN  2048
#define DHEAD 64
#define NKT   (SLEN / 64)

typedef short bf16x8 __attribute__((ext_vector_type(8)));
typedef float f32x4  __attribute__((ext_vector_type(4)));
typedef unsigned short u16x8 __attribute__((ext_vector_type(8)));

static __device__ __forceinline__ unsigned short f2bf(float f) {
    union { float f; unsigned int u; } x; x.f = f;
    return (unsigned short)((x.u + 0x7FFFu + ((x.u >> 16) & 1u)) >> 16);  // RNE
}

static __device__ __forceinline__ void gl_lds16(const void* g, void* l) {
    __builtin_amdgcn_global_load_lds(
        (const __attribute__((address_space(1))) unsigned int*)g,
        (__attribute__((address_space(3))) unsigned int*)l, 16, 0, 0);
}

// ---------------- prepass: fp32 -> bf16 (Q scaled; V transposed to [bh][d][s]) ----
__global__ __launch_bounds__(256)
void prep(const float* __restrict__ Q, const float* __restrict__ K,
          const float* __restrict__ V, unsigned short* __restrict__ Qb,
          unsigned short* __restrict__ Kb, unsigned short* __restrict__ Vt)
{
    __shared__ unsigned short T[64][72];
    const int tid = threadIdx.x;
    const int st = blockIdx.x, bh = blockIdx.y;
    const size_t base = ((size_t)bh * SLEN + (size_t)st * 64) * DHEAD;

    #pragma unroll
    for (int it = 0; it < 4; ++it) {
        const int idx = it * 1024 + tid * 4;
        const int s = idx >> 6, d = idx & 63;
        float4 q4 = *(const float4*)(Q + base + idx);
        float4 k4 = *(const float4*)(K + base + idx);
        float4 v4 = *(const float4*)(V + base + idx);
        ushort4 qo, ko;
        qo.x = f2bf(q4.x * 0.125f); qo.y = f2bf(q4.y * 0.125f);
        qo.z = f2bf(q4.z * 0.125f); qo.w = f2bf(q4.w * 0.125f);
        ko.x = f2bf(k4.x); ko.y = f2bf(k4.y);
        ko.z = f2bf(k4.z); ko.w = f2bf(k4.w);
        *(ushort4*)(Qb + base + idx) = qo;
        *(ushort4*)(Kb + base + idx) = ko;
        T[d + 0][s] = f2bf(v4.x);
        T[d + 1][s] = f2bf(v4.y);
        T[d + 2][s] = f2bf(v4.z);
        T[d + 3][s] = f2bf(v4.w);
    }
    __syncthreads();
    const int d = tid >> 2, sc = (tid & 3) * 16;
    unsigned short* orow = Vt + ((size_t)bh * DHEAD + d) * SLEN + (size_t)st * 64 + sc;
    *(u16x8*)(orow)     = *(const u16x8*)&T[d][sc];
    *(u16x8*)(orow + 8) = *(const u16x8*)&T[d][sc + 8];
}

// ---------------- main fused attention, bf16 inputs from ws ----------------------
__global__ __launch_bounds__(256)
void sdpa_fwd2(const unsigned short* __restrict__ Qb,
               const unsigned short* __restrict__ Kb,
               const unsigned short* __restrict__ VtG,
               const float* __restrict__ M, float* __restrict__ O)
{
    __shared__ unsigned short Kt[2][64][64];   // K tile [kv][d], XOR-swizzled 16B slots
    __shared__ unsigned short Vt[2][64][64];   // V^T tile [d][kv], same swizzle
    __shared__ unsigned short Plds[4][16][72]; // per-wave P relayout

    const int tid  = threadIdx.x;
    const int wave = tid >> 6, lane = tid & 63;
    const int lg   = lane >> 4, ln = lane & 15;
    const int qtile = blockIdx.x, bh = blockIdx.y;
    const int qbase = qtile * 64 + wave * 16;
    const size_t hoff = (size_t)bh * SLEN * DHEAD;

    // Q fragments: already scaled + bf16. A-layout: row=ln, k=32*ks+8*lg+j
    bf16x8 qf[2];
    {
        const unsigned short* qp = Qb + hoff + (size_t)(qbase + ln) * DHEAD + lg * 8;
        qf[0] = *(const bf16x8*)(qp);
        qf[1] = *(const bf16x8*)(qp + 32);
    }

    // staging geometry: thread -> (row srow within 32-row chunk, 16B slot), source
    // pre-swizzled so that linear LDS + swizzled read = conflict-free (rule #21)
    const int srow = tid >> 3;                    // 0..31
    const int slot = tid & 7;
    const int swz  = ((slot ^ (srow & 7)) << 4);  // byte offset of source 16B chunk
    const char* kgb = (const char*)(Kb + hoff);
    const char* vgb = (const char*)(VtG + (size_t)bh * DHEAD * SLEN);

    f32x4 oacc[4];
    #pragma unroll
    for (int dn = 0; dn < 4; ++dn) oacc[dn] = (f32x4){0.f, 0.f, 0.f, 0.f};
    float m_i[4] = {-INFINITY, -INFINITY, -INFINITY, -INFINITY};
    float l_i[4] = {0.f, 0.f, 0.f, 0.f};

    // ---- prologue: stage tile 0 into buf 0 ----
    {
        gl_lds16(kgb + (size_t)(srow) * 128 + swz,            (char*)&Kt[0][0][0] + wave * 1024);
        gl_lds16(kgb + (size_t)(srow + 32) * 128 + swz,       (char*)&Kt[0][0][0] + 4096 + wave * 1024);
        gl_lds16(vgb + (size_t)(srow) * (SLEN * 2) + swz,     (char*)&Vt[0][0][0] + wave * 1024);
        gl_lds16(vgb + (size_t)(srow + 32) * (SLEN * 2) + swz,(char*)&Vt[0][0][0] + 4096 + wave * 1024);
    }
    __syncthreads();

    int buf = 0;
    for (int kt = 0; kt < NKT; ++kt) {
        // ---- issue next tile's async loads (hidden under this tile's compute) ----
        if (kt + 1 < NKT) {
            const int b = buf ^ 1;
            const size_t kb = (size_t)(kt + 1) * 64;
            gl_lds16(kgb + (kb + srow) * 128 + swz,                              (char*)&Kt[b][0][0] + wave * 1024);
            gl_lds16(kgb + (kb + srow + 32) * 128 + swz,                         (char*)&Kt[b][0][0] + 4096 + wave * 1024);
            gl_lds16(vgb + (size_t)(srow) * (SLEN * 2) + (kt + 1) * 128 + swz,   (char*)&Vt[b][0][0] + wave * 1024);
            gl_lds16(vgb + (size_t)(srow + 32) * (SLEN * 2) + (kt + 1) * 128 + swz,(char*)&Vt[b][0][0] + 4096 + wave * 1024);
        }
        const int kbase = kt * 64;

        // ---- QK^T: S[16 q][64 kv], swizzled K reads ----
        f32x4 sc[4];
        #pragma unroll
        for (int nt = 0; nt < 4; ++nt) {
            f32x4 acc = (f32x4){0.f, 0.f, 0.f, 0.f};
            #pragma unroll
            for (int ks = 0; ks < 2; ++ks) {
                const char* kr = (const char*)&Kt[buf][nt * 16 + ln][0];
                bf16x8 kf = *(const bf16x8*)(kr + ((((ks * 4 + lg) ^ (ln & 7)) << 4)));
                acc = __builtin_amdgcn_mfma_f32_16x16x32_bf16(qf[ks], kf, acc, 0, 0, 0);
            }
            sc[nt] = acc;
        }

        // ---- additive mask ----
        #pragma unroll
        for (int i = 0; i < 4; ++i) {
            const float* mrow = M + (size_t)(qbase + 4 * lg + i) * SLEN + kbase;
            #pragma unroll
            for (int nt = 0; nt < 4; ++nt)
                sc[nt][i] += mrow[nt * 16 + ln];
        }

        // ---- online softmax ----
        float mnew[4], alpha[4];
        #pragma unroll
        for (int i = 0; i < 4; ++i) {
            float tm = fmaxf(fmaxf(sc[0][i], sc[1][i]), fmaxf(sc[2][i], sc[3][i]));
            tm = fmaxf(tm, __shfl_xor(tm, 1));
            tm = fmaxf(tm, __shfl_xor(tm, 2));
            tm = fmaxf(tm, __shfl_xor(tm, 4));
            tm = fmaxf(tm, __shfl_xor(tm, 8));
            mnew[i]  = fmaxf(m_i[i], tm);
            alpha[i] = __expf(m_i[i] - mnew[i]);
            m_i[i]   = mnew[i];
        }

        #pragma unroll
        for (int nt = 0; nt < 4; ++nt) {
            #pragma unroll
            for (int i = 0; i < 4; ++i) {
                float p = __expf(sc[nt][i] - mnew[i]);
                sc[nt][i] = p;
                Plds[wave][4 * lg + i][nt * 16 + ln] = f2bf(p);
            }
        }

        #pragma unroll
        for (int i = 0; i < 4; ++i) {
            float ts = (sc[0][i] + sc[1][i]) + (sc[2][i] + sc[3][i]);
            ts += __shfl_xor(ts, 1);
            ts += __shfl_xor(ts, 2);
            ts += __shfl_xor(ts, 4);
            ts += __shfl_xor(ts, 8);
            l_i[i] = l_i[i] * alpha[i] + ts;
            #pragma unroll
            for (int dn = 0; dn < 4; ++dn) oacc[dn][i] *= alpha[i];
        }

        // ---- PV: swizzled V^T reads ----
        #pragma unroll
        for (int ks = 0; ks < 2; ++ks) {
            bf16x8 pa = *(const bf16x8*)&Plds[wave][ln][ks * 32 + lg * 8];
            #pragma unroll
            for (int dn = 0; dn < 4; ++dn) {
                const char* vr = (const char*)&Vt[buf][dn * 16 + ln][0];
                bf16x8 vb = *(const bf16x8*)(vr + ((((ks * 4 + lg) ^ (ln & 7)) << 4)));
                oacc[dn] = __builtin_amdgcn_mfma_f32_16x16x32_bf16(pa, vb, oacc[dn], 0, 0, 0);
            }
        }

        __syncthreads();   // drains this wave's async stage (hidden) + all readers done
        buf ^= 1;
    }

    #pragma unroll
    for (int i = 0; i < 4; ++i) {
        float inv = 1.0f / l_i[i];
        float* op = O + hoff + (size_t)(qbase + 4 * lg + i) * DHEAD;
        #pragma unroll
        for (int dn = 0; dn < 4; ++dn)
            op[dn * 16 + ln] = oacc[dn][i] * inv;
    }
}

// ---------------- fallback (round-1 kernel) if ws is too small -------------------
__global__ __launch_bounds__(256)
void sdpa_fwd(const float* __restrict__ Q, const float* __restrict__ K,
              const float* __restrict__ V, const float* __restrict__ M,
              float* __restrict__ O)
{
    __shared__ unsigned short Klds[64][72];
    __shared__ unsigned short Vt[64][72];
    __shared__ unsigned short Plds[4][16][72];

    const int tid  = threadIdx.x;
    const int wave = tid >> 6, lane = tid & 63;
    const int lg   = lane >> 4, ln = lane & 15;
    const int qtile = blockIdx.x, bh = blockIdx.y;
    const int qbase = qtile * 64 + wave * 16;
    const size_t hoff = (size_t)bh * SLEN * DHEAD;

    bf16x8 qf[2];
    {
        const float* qp = Q + hoff + (size_t)(qbase + ln) * DHEAD;
        #pragma unroll
        for (int ks = 0; ks < 2; ++ks) {
            float4 a = *(const float4*)(qp + ks * 32 + lg * 8);
            float4 b = *(const float4*)(qp + ks * 32 + lg * 8 + 4);
            qf[ks][0] = (short)f2bf(a.x * 0.125f); qf[ks][1] = (short)f2bf(a.y * 0.125f);
            qf[ks][2] = (short)f2bf(a.z * 0.125f); qf[ks][3] = (short)f2bf(a.w * 0.125f);
            qf[ks][4] = (short)f2bf(b.x * 0.125f); qf[ks][5] = (short)f2bf(b.y * 0.125f);
            qf[ks][6] = (short)f2bf(b.z * 0.125f); qf[ks][7] = (short)f2bf(b.w * 0.125f);
        }
    }

    f32x4 oacc[4];
    #pragma unroll
    for (int dn = 0; dn < 4; ++dn) oacc[dn] = (f32x4){0.f, 0.f, 0.f, 0.f};
    float m_i[4] = {-INFINITY, -INFINITY, -INFINITY, -INFINITY};
    float l_i[4] = {0.f, 0.f, 0.f, 0.f};

    for (int kt = 0; kt < NKT; ++kt) {
        const int kbase = kt * 64;
        __syncthreads();
        {
            const float* kp = K + hoff + (size_t)kbase * DHEAD;
            const float* vp = V + hoff + (size_t)kbase * DHEAD;
            #pragma unroll
            for (int it = 0; it < 4; ++it) {
                int flat = it * 1024 + tid * 4;
                int r = flat >> 6, c = flat & 63;
                float4 kv4 = *(const float4*)(kp + flat);
                float4 vv4 = *(const float4*)(vp + flat);
                ushort4 kb;
                kb.x = f2bf(kv4.x); kb.y = f2bf(kv4.y);
                kb.z = f2bf(kv4.z); kb.w = f2bf(kv4.w);
                *(ushort4*)&Klds[r][c] = kb;
                Vt[c + 0][r] = f2bf(vv4.x); Vt[c + 1][r] = f2bf(vv4.y);
                Vt[c + 2][r] = f2bf(vv4.z); Vt[c + 3][r] = f2bf(vv4.w);
            }
        }
        __syncthreads();

        f32x4 sc[4];
        #pragma unroll
        for (int nt = 0; nt < 4; ++nt) {
            f32x4 acc = (f32x4){0.f, 0.f, 0.f, 0.f};
            #pragma unroll
            for (int ks = 0; ks < 2; ++ks) {
                bf16x8 kf = *(const bf16x8*)&Klds[nt * 16 + ln][ks * 32 + lg * 8];
                acc = __builtin_amdgcn_mfma_f32_16x16x32_bf16(qf[ks], kf, acc, 0, 0, 0);
            }
            sc[nt] = acc;
        }
        #pragma unroll
        for (int i = 0; i < 4; ++i) {
            const float* mrow = M + (size_t)(qbase + 4 * lg + i) * SLEN + kbase;
            #pragma unroll
            for (int nt = 0; nt < 4; ++nt) sc[nt][i] += mrow[nt * 16 + ln];
        }
        float mnew[4], alpha[4];
        #pragma unroll
        for (int i = 0; i < 4; ++i) {
            float tm = fmaxf(fmaxf(sc[0][i], sc[1][i]), fmaxf(sc[2][i], sc[3][i]));
            tm = fmaxf(tm, __shfl_xor(tm, 1));
            tm = fmaxf(tm, __shfl_xor(tm, 2));
            tm = fmaxf(tm, __shfl_xor(tm, 4));
            tm = fmaxf(tm, __shfl_xor(tm, 8));
            mnew[i] = fmaxf(m_i[i], tm);
            alpha[i] = __expf(m_i[i] - mnew[i]);
            m_i[i] = mnew[i];
        }
        #pragma unroll
        for (int nt = 0; nt < 4; ++nt)
            #pragma unroll
            for (int i = 0; i < 4; ++i) {
                float p = __expf(sc[nt][i] - mnew[i]);
                sc[nt][i] = p;
                Plds[wave][4 * lg + i][nt * 16 + ln] = f2bf(p);
            }
        #pragma unroll
        for (int i = 0; i < 4; ++i) {
            float ts = (sc[0][i] + sc[1][i]) + (sc[2][i] + sc[3][i]);
            ts += __shfl_xor(ts, 1);
            ts += __shfl_xor(ts, 2);
            ts += __shfl_xor(ts, 4);
            ts += __shfl_xor(ts, 8);
            l_i[i] = l_i[i] * alpha[i] + ts;
            #pragma unroll
            for (int dn = 0; dn < 4; ++dn) oacc[dn][i] *= alpha[i];
        }
        #pragma unroll
        for (int ks = 0; ks < 2; ++ks) {
            bf16x8 pa = *(const bf16x8*)&Plds[wave][ln][ks * 32 + lg * 8];
            #pragma unroll
            for (int dn = 0; dn < 4; ++dn) {
                bf16x8 vb = *(const bf16x8*)&Vt[dn * 16 + ln][ks * 32 + lg * 8];
                oacc[dn] = __builtin_amdgcn_mfma_f32_16x16x32_bf16(pa, vb, oacc[dn], 0, 0, 0);
            }
        }
    }
    #pragma unroll
    for (int i = 0; i < 4; ++i) {
        float inv = 1.0f / l_i[i];
        float* op = O + hoff + (size_t)(qbase + 4 * lg + i) * DHEAD;
        #pragma unroll
        for (int dn = 0; dn < 4; ++dn) op[dn * 16 + ln] = oacc[dn][i] * inv;
    }
}

extern "C" void kernel_launch(void* const* d_in, const int* in_sizes, int n_in,
                              void* d_out, int out_size, void* d_ws, size_t ws_size,
                              hipStream_t stream) {
    const float* q = (const float*)d_in[0];
    const float* k = (const float*)d_in[1];
    const float* v = (const float*)d_in[2];
    const float* m = (const float*)d_in[3];
    float* o = (float*)d_out;

    const int bh = in_sizes[0] / (SLEN * DHEAD);
    const size_t H = (size_t)bh * SLEN * DHEAD;
    dim3 grid(SLEN / 64, bh);

    if (ws_size >= 3 * H * sizeof(unsigned short)) {
        unsigned short* qb = (unsigned short*)d_ws;
        unsigned short* kb = qb + H;
        unsigned short* vt = kb + H;
        prep<<<grid, 256, 0, stream>>>(q, k, v, qb, kb, vt);
        sdpa_fwd2<<<grid, 256, 0, stream>>>(qb, kb, vt, m, o);
    } else {
        sdpa_fwd<<<grid, 256, 0, stream>>>(q, k, v, m, o);
    }
}

// Round 4
// 91.110 us; speedup vs baseline: 1.5511x; 1.1706x over previous
//
#include <hip/hip_runtime.h>
#include <stdint.h>

#define SLEN  2048
#define DHEAD 64
#define NKT   (SLEN / 64)
#define LOG2E 1.4426950408889634f
#define QSCALE (0.125f * LOG2E)

typedef short bf16x8 __attribute__((ext_vector_type(8)));
typedef float f32x4  __attribute__((ext_vector_type(4)));
typedef float f32x16 __attribute__((ext_vector_type(16)));
typedef unsigned short u16x8 __attribute__((ext_vector_type(8)));

static __device__ __forceinline__ unsigned short f2bf(float f) {
    union { float f; unsigned int u; } x; x.f = f;
    return (unsigned short)((x.u + 0x7FFFu + ((x.u >> 16) & 1u)) >> 16);  // RNE
}

static __device__ __forceinline__ unsigned pack_bf16(float lo, float hi) {
    return (unsigned)f2bf(lo) | ((unsigned)f2bf(hi) << 16);
}

static __device__ __forceinline__ void gl_lds16(const void* g, void* l) {
    __builtin_amdgcn_global_load_lds(
        (const __attribute__((address_space(1))) unsigned int*)g,
        (__attribute__((address_space(3))) unsigned int*)l, 16, 0, 0);
}

// ---------------- prepass: fp32 -> bf16 (Q scaled by 1/8*log2e; V transposed) ----
__global__ __launch_bounds__(256)
void prep(const float* __restrict__ Q, const float* __restrict__ K,
          const float* __restrict__ V, unsigned short* __restrict__ Qb,
          unsigned short* __restrict__ Kb, unsigned short* __restrict__ Vt)
{
    __shared__ unsigned short T[64][72];
    const int tid = threadIdx.x;
    const int st = blockIdx.x, bh = blockIdx.y;
    const size_t base = ((size_t)bh * SLEN + (size_t)st * 64) * DHEAD;

    #pragma unroll
    for (int it = 0; it < 4; ++it) {
        const int idx = it * 1024 + tid * 4;
        const int s = idx >> 6, d = idx & 63;
        float4 q4 = *(const float4*)(Q + base + idx);
        float4 k4 = *(const float4*)(K + base + idx);
        float4 v4 = *(const float4*)(V + base + idx);
        ushort4 qo, ko;
        qo.x = f2bf(q4.x * QSCALE); qo.y = f2bf(q4.y * QSCALE);
        qo.z = f2bf(q4.z * QSCALE); qo.w = f2bf(q4.w * QSCALE);
        ko.x = f2bf(k4.x); ko.y = f2bf(k4.y);
        ko.z = f2bf(k4.z); ko.w = f2bf(k4.w);
        *(ushort4*)(Qb + base + idx) = qo;
        *(ushort4*)(Kb + base + idx) = ko;
        T[d + 0][s] = f2bf(v4.x);
        T[d + 1][s] = f2bf(v4.y);
        T[d + 2][s] = f2bf(v4.z);
        T[d + 3][s] = f2bf(v4.w);
    }
    __syncthreads();
    const int d = tid >> 2, sc = (tid & 3) * 16;
    unsigned short* orow = Vt + ((size_t)bh * DHEAD + d) * SLEN + (size_t)st * 64 + sc;
    *(u16x8*)(orow)     = *(const u16x8*)&T[d][sc];
    *(u16x8*)(orow + 8) = *(const u16x8*)&T[d][sc + 8];
}

// ---------------- main: swapped 32x32 MFMA, in-register softmax -------------------
__global__ __launch_bounds__(128)
void sdpa_fwd4(const unsigned short* __restrict__ Qb,
               const unsigned short* __restrict__ Kb,
               const unsigned short* __restrict__ VtG,
               const float* __restrict__ M, float* __restrict__ O)
{
    __shared__ unsigned short Kt[2][64][64];   // K tile [kv][d], swizzled 16B slots
    __shared__ unsigned short Vt[2][64][64];   // V^T tile [d][kv], same swizzle

    const int tid  = threadIdx.x;
    const int wave = tid >> 6, lane = tid & 63;
    const int l31  = lane & 31, hi = lane >> 5;

    // XCD-aware bijective swizzle (768 % 8 == 0): 3 heads per XCD -> K/V L2-resident
    const int nwg  = gridDim.x;
    int wg = blockIdx.x;
    if ((nwg & 7) == 0) wg = (wg & 7) * (nwg >> 3) + (wg >> 3);
    const int qtile = wg & 31, bh = wg >> 5;

    const int q = qtile * 64 + wave * 32 + l31;        // this lane's q row
    const size_t hoff = (size_t)bh * SLEN * DHEAD;

    // Q B-fragments: col=q (lane-local), k = 16*ds + 8*hi + j
    bf16x8 qf[4];
    {
        const unsigned short* qp = Qb + hoff + (size_t)q * DHEAD + hi * 8;
        #pragma unroll
        for (int ds = 0; ds < 4; ++ds) qf[ds] = *(const bf16x8*)(qp + ds * 16);
    }

    // staging geometry (linear LDS dest; source pre-swizzled, rule #21)
    const char* kgb = (const char*)(Kb + hoff);
    const char* vgb = (const char*)(VtG + (size_t)bh * DHEAD * SLEN);
    unsigned koff[4], voff[4], ldst[4];
    #pragma unroll
    for (int i = 0; i < 4; ++i) {
        const unsigned o = i * 2048 + wave * 1024 + lane * 16;
        const unsigned row = o >> 7;
        const unsigned slot = ((o >> 4) & 7) ^ (row & 7);
        koff[i] = row * 128 + slot * 16;     // within K tile (row=kv)
        voff[i] = row * 4096 + slot * 16;    // within V^T head (row=d, stride S*2B)
        ldst[i] = i * 2048 + wave * 1024;    // wave-uniform LDS base
    }

    f32x16 oacc[2];
    #pragma unroll
    for (int db = 0; db < 2; ++db)
        #pragma unroll
        for (int r = 0; r < 16; ++r) oacc[db][r] = 0.f;
    float m_i = -INFINITY, l_i = 0.f;

    // prologue: stage tile 0 -> buf 0
    #pragma unroll
    for (int i = 0; i < 4; ++i) {
        gl_lds16(kgb + koff[i], (char*)Kt + ldst[i]);
        gl_lds16(vgb + voff[i], (char*)Vt + ldst[i]);
    }
    __syncthreads();

    int buf = 0;
    for (int kt = 0; kt < NKT; ++kt) {
        // ---- issue next tile's async loads ----
        if (kt + 1 < NKT) {
            const unsigned bo = (buf ^ 1) * 8192;
            #pragma unroll
            for (int i = 0; i < 4; ++i) {
                gl_lds16(kgb + (size_t)(kt + 1) * 8192 + koff[i], (char*)Kt + bo + ldst[i]);
                gl_lds16(vgb + (size_t)(kt + 1) * 128  + voff[i], (char*)Vt + bo + ldst[i]);
            }
        }

        // ---- mask rows (lane-local q row, kv-contiguous float4s) ----
        const float* mrow = M + (size_t)q * SLEN + kt * 64;
        float4 mq[8];
        #pragma unroll
        for (int sb = 0; sb < 2; ++sb)
            #pragma unroll
            for (int g = 0; g < 4; ++g)
                mq[sb * 4 + g] = *(const float4*)(mrow + sb * 32 + g * 8 + hi * 4);

        // ---- QK^T swapped: sc[sb] = S^T[kv 32][q 32] ----
        f32x16 sc[2];
        const char* kl = (const char*)Kt + buf * 8192;
        #pragma unroll
        for (int sb = 0; sb < 2; ++sb) {
            f32x16 acc;
            #pragma unroll
            for (int r = 0; r < 16; ++r) acc[r] = 0.f;
            const int row = sb * 32 + l31;
            #pragma unroll
            for (int ds = 0; ds < 4; ++ds) {
                const int slot = (ds * 2 + hi) ^ (row & 7);
                bf16x8 kf = *(const bf16x8*)(kl + row * 128 + slot * 16);
                acc = __builtin_amdgcn_mfma_f32_32x32x16_bf16(kf, qf[ds], acc, 0, 0, 0);
            }
            sc[sb] = acc;
        }

        // ---- mask add in log2 domain (mask is zeros here; exact indexing kept) ----
        #pragma unroll
        for (int sb = 0; sb < 2; ++sb)
            #pragma unroll
            for (int r = 0; r < 16; ++r)
                sc[sb][r] = fmaf(mq[sb * 4 + (r >> 2)][r & 3], LOG2E, sc[sb][r]);

        // ---- row max: in-reg tree + one shfl_xor(32) ----
        float red[16];
        #pragma unroll
        for (int r = 0; r < 16; ++r) red[r] = fmaxf(sc[0][r], sc[1][r]);
        #pragma unroll
        for (int r = 0; r < 8; ++r) red[r] = fmaxf(red[r], red[r + 8]);
        #pragma unroll
        for (int r = 0; r < 4; ++r) red[r] = fmaxf(red[r], red[r + 4]);
        red[0] = fmaxf(fmaxf(red[0], red[2]), fmaxf(red[1], red[3]));
        const float mtile = fmaxf(red[0], __shfl_xor(red[0], 32));

        // ---- T13 defer-max: skip rescale while tile max within 2^11 headroom ----
        if (!__all(mtile - m_i <= 11.0f)) {
            const float mnew = fmaxf(m_i, mtile);
            const float alpha = __builtin_amdgcn_exp2f(m_i - mnew);
            l_i *= alpha;
            #pragma unroll
            for (int db = 0; db < 2; ++db)
                #pragma unroll
                for (int r = 0; r < 16; ++r) oacc[db][r] *= alpha;
            m_i = mnew;
        }

        // ---- p = exp2(s' - m') ----
        #pragma unroll
        for (int sb = 0; sb < 2; ++sb)
            #pragma unroll
            for (int r = 0; r < 16; ++r)
                sc[sb][r] = __builtin_amdgcn_exp2f(sc[sb][r] - m_i);

        // ---- row sum: tree + shfl ----
        float sr[16];
        #pragma unroll
        for (int r = 0; r < 16; ++r) sr[r] = sc[0][r] + sc[1][r];
        #pragma unroll
        for (int r = 0; r < 8; ++r) sr[r] += sr[r + 8];
        #pragma unroll
        for (int r = 0; r < 4; ++r) sr[r] += sr[r + 4];
        sr[0] = (sr[0] + sr[2]) + (sr[1] + sr[3]);
        l_i += sr[0] + __shfl_xor(sr[0], 32);

        // ---- P -> bf16 B-frags: manual pack + shfl_xor(32) exchange -------------
        // own regs 8e+0..3 hold kv 16ks+4hi+{0..3}; regs 8e+4..7 hold 16ks+8+4hi+{..}
        unsigned wa[8], wb[8];
        #pragma unroll
        for (int sb = 0; sb < 2; ++sb)
            #pragma unroll
            for (int g = 0; g < 4; ++g) {
                wa[sb * 4 + g] = pack_bf16(sc[sb][4 * g + 0], sc[sb][4 * g + 1]);
                wb[sb * 4 + g] = pack_bf16(sc[sb][4 * g + 2], sc[sb][4 * g + 3]);
            }
        bf16x8 pf[4];
        #pragma unroll
        for (int ks = 0; ks < 4; ++ks) {
            const int base = (ks >> 1) * 4 + (ks & 1) * 2;
            const unsigned a = wa[base], b = wa[base + 1];
            const unsigned c = wb[base], d = wb[base + 1];
            const unsigned z0 = hi ? a : b;
            const unsigned z1 = hi ? c : d;
            const unsigned w0 = (unsigned)__shfl_xor((int)z0, 32);
            const unsigned w1 = (unsigned)__shfl_xor((int)z1, 32);
            union { unsigned u[4]; bf16x8 v; } f;
            f.u[0] = hi ? w0 : a;
            f.u[1] = hi ? w1 : c;
            f.u[2] = hi ? b : w0;
            f.u[3] = hi ? d : w1;
            pf[ks] = f.v;
        }

        // ---- PV swapped: O^T[d 32][q 32] += V^T * P^T ----
        const char* vl = (const char*)Vt + buf * 8192;
        #pragma unroll
        for (int db = 0; db < 2; ++db) {
            const int row = db * 32 + l31;
            #pragma unroll
            for (int ks = 0; ks < 4; ++ks) {
                const int slot = (ks * 2 + hi) ^ (row & 7);
                bf16x8 vf = *(const bf16x8*)(vl + row * 128 + slot * 16);
                oacc[db] = __builtin_amdgcn_mfma_f32_32x32x16_bf16(vf, pf[ks], oacc[db], 0, 0, 0);
            }
        }

        __syncthreads();   // drains async stage + all LDS readers of buf
        buf ^= 1;
    }

    // ---- epilogue: normalize, store ----
    const float inv = 1.0f / l_i;
    float* op = O + hoff + (size_t)q * DHEAD;
    #pragma unroll
    for (int db = 0; db < 2; ++db)
        #pragma unroll
        for (int g = 0; g < 4; ++g) {
            float4 o4;
            o4.x = oacc[db][4 * g + 0] * inv;
            o4.y = oacc[db][4 * g + 1] * inv;
            o4.z = oacc[db][4 * g + 2] * inv;
            o4.w = oacc[db][4 * g + 3] * inv;
            *(float4*)(op + db * 32 + g * 8 + hi * 4) = o4;
        }
}

// ---------------- fallback (round-1 kernel) if ws is too small -------------------
__global__ __launch_bounds__(256)
void sdpa_fwd(const float* __restrict__ Q, const float* __restrict__ K,
              const float* __restrict__ V, const float* __restrict__ M,
              float* __restrict__ O)
{
    __shared__ unsigned short Klds[64][72];
    __shared__ unsigned short Vtl[64][72];
    __shared__ unsigned short Plds[4][16][72];

    const int tid  = threadIdx.x;
    const int wave = tid >> 6, lane = tid & 63;
    const int lg   = lane >> 4, ln = lane & 15;
    const int qtile = blockIdx.x, bh = blockIdx.y;
    const int qbase = qtile * 64 + wave * 16;
    const size_t hoff = (size_t)bh * SLEN * DHEAD;

    bf16x8 qf[2];
    {
        const float* qp = Q + hoff + (size_t)(qbase + ln) * DHEAD;
        #pragma unroll
        for (int ks = 0; ks < 2; ++ks) {
            float4 a = *(const float4*)(qp + ks * 32 + lg * 8);
            float4 b = *(const float4*)(qp + ks * 32 + lg * 8 + 4);
            qf[ks][0] = (short)f2bf(a.x * 0.125f); qf[ks][1] = (short)f2bf(a.y * 0.125f);
            qf[ks][2] = (short)f2bf(a.z * 0.125f); qf[ks][3] = (short)f2bf(a.w * 0.125f);
            qf[ks][4] = (short)f2bf(b.x * 0.125f); qf[ks][5] = (short)f2bf(b.y * 0.125f);
            qf[ks][6] = (short)f2bf(b.z * 0.125f); qf[ks][7] = (short)f2bf(b.w * 0.125f);
        }
    }

    f32x4 oacc[4];
    #pragma unroll
    for (int dn = 0; dn < 4; ++dn) oacc[dn] = (f32x4){0.f, 0.f, 0.f, 0.f};
    float m_i[4] = {-INFINITY, -INFINITY, -INFINITY, -INFINITY};
    float l_i[4] = {0.f, 0.f, 0.f, 0.f};

    for (int kt = 0; kt < NKT; ++kt) {
        const int kbase = kt * 64;
        __syncthreads();
        {
            const float* kp = K + hoff + (size_t)kbase * DHEAD;
            const float* vp = V + hoff + (size_t)kbase * DHEAD;
            #pragma unroll
            for (int it = 0; it < 4; ++it) {
                int flat = it * 1024 + tid * 4;
                int r = flat >> 6, c = flat & 63;
                float4 kv4 = *(const float4*)(kp + flat);
                float4 vv4 = *(const float4*)(vp + flat);
                ushort4 kb;
                kb.x = f2bf(kv4.x); kb.y = f2bf(kv4.y);
                kb.z = f2bf(kv4.z); kb.w = f2bf(kv4.w);
                *(ushort4*)&Klds[r][c] = kb;
                Vtl[c + 0][r] = f2bf(vv4.x); Vtl[c + 1][r] = f2bf(vv4.y);
                Vtl[c + 2][r] = f2bf(vv4.z); Vtl[c + 3][r] = f2bf(vv4.w);
            }
        }
        __syncthreads();

        f32x4 sc[4];
        #pragma unroll
        for (int nt = 0; nt < 4; ++nt) {
            f32x4 acc = (f32x4){0.f, 0.f, 0.f, 0.f};
            #pragma unroll
            for (int ks = 0; ks < 2; ++ks) {
                bf16x8 kf = *(const bf16x8*)&Klds[nt * 16 + ln][ks * 32 + lg * 8];
                acc = __builtin_amdgcn_mfma_f32_16x16x32_bf16(qf[ks], kf, acc, 0, 0, 0);
            }
            sc[nt] = acc;
        }
        #pragma unroll
        for (int i = 0; i < 4; ++i) {
            const float* mrow = M + (size_t)(qbase + 4 * lg + i) * SLEN + kbase;
            #pragma unroll
            for (int nt = 0; nt < 4; ++nt) sc[nt][i] += mrow[nt * 16 + ln];
        }
        float mnew[4], alpha[4];
        #pragma unroll
        for (int i = 0; i < 4; ++i) {
            float tm = fmaxf(fmaxf(sc[0][i], sc[1][i]), fmaxf(sc[2][i], sc[3][i]));
            tm = fmaxf(tm, __shfl_xor(tm, 1));
            tm = fmaxf(tm, __shfl_xor(tm, 2));
            tm = fmaxf(tm, __shfl_xor(tm, 4));
            tm = fmaxf(tm, __shfl_xor(tm, 8));
            mnew[i] = fmaxf(m_i[i], tm);
            alpha[i] = __expf(m_i[i] - mnew[i]);
            m_i[i] = mnew[i];
        }
        #pragma unroll
        for (int nt = 0; nt < 4; ++nt)
            #pragma unroll
            for (int i = 0; i < 4; ++i) {
                float p = __expf(sc[nt][i] - mnew[i]);
                sc[nt][i] = p;
                Plds[wave][4 * lg + i][nt * 16 + ln] = f2bf(p);
            }
        #pragma unroll
        for (int i = 0; i < 4; ++i) {
            float ts = (sc[0][i] + sc[1][i]) + (sc[2][i] + sc[3][i]);
            ts += __shfl_xor(ts, 1);
            ts += __shfl_xor(ts, 2);
            ts += __shfl_xor(ts, 4);
            ts += __shfl_xor(ts, 8);
            l_i[i] = l_i[i] * alpha[i] + ts;
            #pragma unroll
            for (int dn = 0; dn < 4; ++dn) oacc[dn][i] *= alpha[i];
        }
        #pragma unroll
        for (int ks = 0; ks < 2; ++ks) {
            bf16x8 pa = *(const bf16x8*)&Plds[wave][ln][ks * 32 + lg * 8];
            #pragma unroll
            for (int dn = 0; dn < 4; ++dn) {
                bf16x8 vb = *(const bf16x8*)&Vtl[dn * 16 + ln][ks * 32 + lg * 8];
                oacc[dn] = __builtin_amdgcn_mfma_f32_16x16x32_bf16(pa, vb, oacc[dn], 0, 0, 0);
            }
        }
    }
    #pragma unroll
    for (int i = 0; i < 4; ++i) {
        float inv = 1.0f / l_i[i];
        float* op = O + hoff + (size_t)(qbase + 4 * lg + i) * DHEAD;
        #pragma unroll
        for (int dn = 0; dn < 4; ++dn) op[dn * 16 + ln] = oacc[dn][i] * inv;
    }
}

extern "C" void kernel_launch(void* const* d_in, const int* in_sizes, int n_in,
                              void* d_out, int out_size, void* d_ws, size_t ws_size,
                              hipStream_t stream) {
    const float* q = (const float*)d_in[0];
    const float* k = (const float*)d_in[1];
    const float* v = (const float*)d_in[2];
    const float* m = (const float*)d_in[3];
    float* o = (float*)d_out;

    const int bh = in_sizes[0] / (SLEN * DHEAD);
    const size_t H = (size_t)bh * SLEN * DHEAD;

    if (ws_size >= 3 * H * sizeof(unsigned short)) {
        unsigned short* qb = (unsigned short*)d_ws;
        unsigned short* kb = qb + H;
        unsigned short* vt = kb + H;
        prep<<<dim3(SLEN / 64, bh), 256, 0, stream>>>(q, k, v, qb, kb, vt);
        sdpa_fwd4<<<(SLEN / 64) * bh, 128, 0, stream>>>(qb, kb, vt, m, o);
    } else {
        sdpa_fwd<<<dim3(SLEN / 64, bh), 256, 0, stream>>>(q, k, v, m, o);
    }
}